// Round 6
// baseline (1353.820 us; speedup 1.0000x reference)
//
#include <hip/hip_runtime.h>
#include <cstddef>

static constexpr int   NN      = 2048;
static constexpr int   TPB_B   = 256;   // build_cost block
static constexpr int   TPB     = 512;   // main kernel block (8 waves)
static constexpr int   NWB     = TPB / 64;          // 8 waves/block
static constexpr int   NB      = 256;               // main grid blocks (1/CU)
static constexpr int   SLOTSTR = 16;                // u64 stride: 1 slot / 128B line
static constexpr int   MAX_IT  = 100;
static constexpr float EPS     = 0.1f;
static constexpr float INV_EPS = 10.0f;
// logf(1/2048 + 1e-8)
static constexpr float LOG_AB  = -7.6245985063594f;
static constexpr float THRESH  = 0.1f;

#define ALOAD(p)     __hip_atomic_load((p),  __ATOMIC_RELAXED, __HIP_MEMORY_SCOPE_AGENT)
#define ASTORE(p, x) __hip_atomic_store((p), (x), __ATOMIC_RELAXED, __HIP_MEMORY_SCOPE_AGENT)

// ---------------------------------------------------------------------------
// Cost matrix build + state zeroing. C[i][j] = sum_d (x[i,d]-y[j,d])^2.
// ---------------------------------------------------------------------------
__global__ __launch_bounds__(TPB_B)
void build_cost(const float* __restrict__ x, const float* __restrict__ y,
                float* __restrict__ C, float* __restrict__ CT,
                float* __restrict__ zz, int c_aligned, int use_ct)
{
    __shared__ float xs[64][65];
    __shared__ float ys[64][65];
    const int t  = threadIdx.x;
    const int bi = blockIdx.y, bj = blockIdx.x;

    // block (0,0) zeroes slotsA|slotsB: 16384 floats = 64 KiB
    if (bi == 0 && bj == 0)
        for (int idx = t; idx < 16384; idx += TPB_B) zz[idx] = 0.0f;

#pragma unroll
    for (int k = 0; k < 16; ++k) {
        int idx = t + TPB_B * k;
        int r = idx >> 6, c = idx & 63;
        xs[r][c] = x[(size_t)(bi * 64 + r) * 64 + c];
        ys[r][c] = y[(size_t)(bj * 64 + r) * 64 + c];
    }
    __syncthreads();

    const int ti0 = (t >> 4) * 4;
    const int tj0 = (t & 15) * 4;
    float acc[4][4] = {};
#pragma unroll 8
    for (int d = 0; d < 64; ++d) {
        float xv[4], yv[4];
#pragma unroll
        for (int k = 0; k < 4; ++k) xv[k] = xs[ti0 + k][d];
#pragma unroll
        for (int l = 0; l < 4; ++l) yv[l] = ys[tj0 + l][d];
#pragma unroll
        for (int k = 0; k < 4; ++k)
#pragma unroll
            for (int l = 0; l < 4; ++l) {
                float df = xv[k] - yv[l];
                acc[k][l] = fmaf(df, df, acc[k][l]);
            }
    }

#pragma unroll
    for (int k = 0; k < 4; ++k) {
        size_t off = (size_t)(bi * 64 + ti0 + k) * NN + bj * 64 + tj0;
        if (c_aligned) {
            *(float4*)(C + off) = make_float4(acc[k][0], acc[k][1], acc[k][2], acc[k][3]);
        } else {
            C[off + 0] = acc[k][0]; C[off + 1] = acc[k][1];
            C[off + 2] = acc[k][2]; C[off + 3] = acc[k][3];
        }
    }
    if (use_ct) {
#pragma unroll
        for (int l = 0; l < 4; ++l) {
            size_t off = (size_t)(bj * 64 + tj0 + l) * NN + bi * 64 + ti0;
            *(float4*)(CT + off) = make_float4(acc[0][l], acc[1][l], acc[2][l], acc[3][l]);
        }
    }
}

// ---------------------------------------------------------------------------
// Helpers
// ---------------------------------------------------------------------------
__device__ __forceinline__ void load_row32(const float* row, int lane,
                                           int aligned, float c[32])
{
    if (aligned) {
        const float4* r4 = (const float4*)row;
#pragma unroll
        for (int k = 0; k < 8; ++k) {
            float4 A = r4[lane + 64 * k];
            c[4*k+0] = A.x; c[4*k+1] = A.y; c[4*k+2] = A.z; c[4*k+3] = A.w;
        }
    } else {
#pragma unroll
        for (int k = 0; k < 8; ++k) {
            const float* p = row + 4 * (lane + 64 * k);
            c[4*k+0] = p[0]; c[4*k+1] = p[1]; c[4*k+2] = p[2]; c[4*k+3] = p[3];
        }
    }
}

__device__ __forceinline__ void lds_row32(const float* sv, int lane, float b[32])
{
    const float4* s4 = (const float4*)sv;
#pragma unroll
    for (int k = 0; k < 8; ++k) {
        float4 A = s4[lane + 64 * k];
        b[4*k+0] = A.x; b[4*k+1] = A.y; b[4*k+2] = A.z; b[4*k+3] = A.w;
    }
}

// wave-level lse of (b-c)*INV_EPS over 2048 elems (32/lane); result on all lanes
__device__ __forceinline__ float wave_lse(float c[32], const float b[32])
{
#pragma unroll
    for (int k = 0; k < 32; ++k) c[k] = (b[k] - c[k]) * INV_EPS;
    float m = c[0];
#pragma unroll
    for (int k = 1; k < 32; ++k) m = fmaxf(m, c[k]);
    float s = 0.0f;
#pragma unroll
    for (int k = 0; k < 32; ++k) s += __expf(c[k] - m);
#pragma unroll
    for (int off = 1; off < 64; off <<= 1) {
        float m2 = __shfl_xor(m, off);
        float s2 = __shfl_xor(s, off);
        float nm = fmaxf(m, m2);
        s = __expf(m - nm) * s + __expf(m2 - nm) * s2;
        m = nm;
    }
    return m + __logf(s);
}

// ---------------------------------------------------------------------------
// Piggybacked flat barrier. Slot line of block b (128 B):
//   u64[0..3] = 8 floats of u (or v) owned by block b
//   u64[4]    = { epoch:u32 (hi) | pdiff:f32 (lo) }
// Post: lanes 0-3 of wave 0 store data, wave-wide vmcnt(0) drain, lane 0
// stores hdr. Poll: threads 0-255 each own one slot; on release, the SAME
// loads fetch the data into LDS sv[] and the pdiffs (wave-reduced -> spd).
// Fence-free: all cross-block traffic uses RELAXED+AGENT bypass atomics, so
// per-XCD L2s (holding C/CT) are never invalidated. Parity double-buffer
// (slotsA/slotsB) + full-barrier polls bound skew to one phase -> no reuse race.
// ---------------------------------------------------------------------------
__device__ __forceinline__ void post_poll(unsigned long long* slots, unsigned epoch,
                                          const float* swave, const float* sdiffw,
                                          float* sv, float* spd, int pdbase)
{
    const int t = threadIdx.x, lane = t & 63, w = t >> 6;
    __syncthreads();                       // swave/sdiffw complete, sv reads done
    if (w == 0) {
        unsigned long long* myslot = slots + (size_t)blockIdx.x * SLOTSTR;
        if (lane < 4) {
            unsigned long long val =
                ((unsigned long long)__float_as_uint(swave[2*lane+1]) << 32) |
                 (unsigned long long)__float_as_uint(swave[2*lane]);
            ASTORE(myslot + lane, val);
        }
        asm volatile("s_waitcnt vmcnt(0)" ::: "memory");   // data acked at LLC
        if (lane == 0) {
            float pd = 0.0f;
#pragma unroll
            for (int k = 0; k < NWB; ++k) pd += sdiffw[k];
            unsigned long long hdr = ((unsigned long long)epoch << 32) |
                                     (unsigned long long)__float_as_uint(pd);
            ASTORE(myslot + 4, hdr);
        }
    }
    if (t < 256) {
        unsigned long long* sl = slots + (size_t)t * SLOTSTR;
        unsigned long long hdr;
        for (;;) {
            hdr = ALOAD(sl + 4);
            bool ok = (unsigned)(hdr >> 32) >= epoch;
            if (__ballot(ok) == ~0ull) break;
            __builtin_amdgcn_s_sleep(1);
        }
        unsigned long long d0 = ALOAD(sl + 0);
        unsigned long long d1 = ALOAD(sl + 1);
        unsigned long long d2 = ALOAD(sl + 2);
        unsigned long long d3 = ALOAD(sl + 3);
        float2* s2 = (float2*)sv;
        s2[4*t+0] = make_float2(__uint_as_float((unsigned)d0),
                                __uint_as_float((unsigned)(d0 >> 32)));
        s2[4*t+1] = make_float2(__uint_as_float((unsigned)d1),
                                __uint_as_float((unsigned)(d1 >> 32)));
        s2[4*t+2] = make_float2(__uint_as_float((unsigned)d2),
                                __uint_as_float((unsigned)(d2 >> 32)));
        s2[4*t+3] = make_float2(__uint_as_float((unsigned)d3),
                                __uint_as_float((unsigned)(d3 >> 32)));
        float pd = __uint_as_float((unsigned)hdr);
#pragma unroll
        for (int off = 1; off < 64; off <<= 1) pd += __shfl_xor(pd, off);
        if (lane == 0) spd[pdbase + w] = pd;
    }
    __syncthreads();                       // sv/spd published to all 8 waves
}

// ---------------------------------------------------------------------------
// Main cooperative kernel. 256 blocks x 512 thr; wave w of block b owns
// row/col i = b*8 + w. u/v live ONLY in slot lines + LDS. Cm may alias out+1.
// ---------------------------------------------------------------------------
__global__ __launch_bounds__(TPB)
void sinkhorn_main(const float* Cm, const float* __restrict__ CT,
                   unsigned long long* __restrict__ slotsA,
                   unsigned long long* __restrict__ slotsB,
                   float* out, int c_aligned, int use_ct)
{
    __shared__ float sv[2048];     // staged u or v (whole vector)
    __shared__ float swave[NWB];   // own 8 values to post
    __shared__ float sdiffw[NWB];  // per-wave |delta| (reused for cost parts)
    __shared__ float sUown[NWB];   // final u of own rows
    __shared__ float spd[8];       // polled pdiff partials: [0..3]=row [4..7]=col
    const int t = threadIdx.x, lane = t & 63, w = t >> 6, b = blockIdx.x;
    const int i = b * NWB + w;

    for (int k = t; k < 2048; k += TPB) sv[k] = 0.0f;   // v = 0
    __syncthreads();

    float uprev = 0.0f, vprev = 0.0f;
    int itend = MAX_IT - 1;

    for (int it = 0; it < MAX_IT; ++it) {
        const unsigned ep = (unsigned)(it + 1);

        // ---- row pass: u_i = eps*(log_a - lse_j((v_j - C_ij)/eps))
        {
            float b32[32], c32[32];
            lds_row32(sv, lane, b32);
            load_row32(Cm + (size_t)i * NN, lane, c_aligned, c32);
            float lse = wave_lse(c32, b32);
            float un = EPS * (LOG_AB - lse);
            if (lane == 0) { swave[w] = un; sdiffw[w] = fabsf(un - uprev); sUown[w] = un; }
            uprev = un;
        }
        post_poll(slotsA, ep, swave, sdiffw, sv, spd, 0);   // sv <- u

        // ---- col pass: v_j = eps*(log_b - lse_i((u_i - C_ij)/eps))
        {
            float b32[32], c32[32];
            lds_row32(sv, lane, b32);
            if (use_ct) {
                load_row32(CT + (size_t)i * NN, lane, 1, c32);
            } else {
#pragma unroll
                for (int k = 0; k < 8; ++k)
#pragma unroll
                    for (int kk = 0; kk < 4; ++kk)
                        c32[4*k+kk] = Cm[(size_t)(4 * (lane + 64 * k) + kk) * NN + i];
            }
            float lse = wave_lse(c32, b32);
            float vn = EPS * (LOG_AB - lse);
            if (lane == 0) { swave[w] = vn; sdiffw[w] = fabsf(vn - vprev); }
            vprev = vn;
        }
        post_poll(slotsB, ep, swave, sdiffw, sv, spd, 4);   // sv <- v

        float diff = spd[0] + spd[1] + spd[2] + spd[3]
                   + spd[4] + spd[5] + spd[6] + spd[7];     // uniform everywhere
        if (diff < THRESH) { itend = it; break; }
    }

    // ---- epilogue: pi = exp((u_i + v_j - C_ij)/eps), cost = sum(pi*C)
    float cpart = 0.0f;
    {
        float b32[32], c32[32];
        lds_row32(sv, lane, b32);                    // sv holds final v
        load_row32(Cm + (size_t)i * NN, lane, c_aligned, c32);
        float ui = sUown[w];
        float* orow = out + 1 + (size_t)i * NN;
#pragma unroll
        for (int k = 0; k < 8; ++k) {
#pragma unroll
            for (int kk = 0; kk < 4; ++kk) {
                float cc = c32[4*k+kk];
                float p  = __expf((ui + b32[4*k+kk] - cc) * INV_EPS);
                cpart = fmaf(p, cc, cpart);
                orow[4 * (lane + 64 * k) + kk] = p;  // safe even if Cm==out+1
            }
        }
    }
#pragma unroll
    for (int off = 1; off < 64; off <<= 1) cpart += __shfl_xor(cpart, off);
    if (lane == 0) sdiffw[w] = cpart;
    __syncthreads();
    const unsigned cep = (unsigned)(itend + 2);      // > any loop epoch, uniform
    if (t == 0) {
        float pc = 0.0f;
#pragma unroll
        for (int k = 0; k < NWB; ++k) pc += sdiffw[k];
        unsigned long long hdr = ((unsigned long long)cep << 32) |
                                 (unsigned long long)__float_as_uint(pc);
        ASTORE(slotsA + (size_t)b * SLOTSTR + 4, hdr);
    }
    if (b == 0) {                                    // only block 0 gathers cost
        if (t < 256) {
            unsigned long long* sl = slotsA + (size_t)t * SLOTSTR;
            unsigned long long hdr;
            for (;;) {
                hdr = ALOAD(sl + 4);
                bool ok = (unsigned)(hdr >> 32) >= cep;
                if (__ballot(ok) == ~0ull) break;
                __builtin_amdgcn_s_sleep(1);
            }
            float pc = __uint_as_float((unsigned)hdr);
#pragma unroll
            for (int off = 1; off < 64; off <<= 1) pc += __shfl_xor(pc, off);
            if (lane == 0) spd[w] = pc;
        }
        __syncthreads();
        if (t == 0) out[0] = spd[0] + spd[1] + spd[2] + spd[3];
    }
}

// ---------------------------------------------------------------------------
extern "C" void kernel_launch(void* const* d_in, const int* in_sizes, int n_in,
                              void* d_out, int out_size, void* d_ws, size_t ws_size,
                              hipStream_t stream)
{
    (void)in_sizes; (void)n_in; (void)out_size;
    const float* x = (const float*)d_in[0];
    const float* y = (const float*)d_in[1];
    float* out = (float*)d_out;
    char*  ws  = (char*)d_ws;

    const size_t CB = (size_t)NN * NN * sizeof(float);   // 16 MiB
    const size_t ZZ = 64 * 1024;

    float *Cm, *CT, *zz;
    int c_aligned, use_ct;
    if (ws_size >= 2 * CB + ZZ) {             // preferred: C, CT, state in ws
        Cm = (float*)ws; CT = (float*)(ws + CB); zz = (float*)(ws + 2 * CB);
        c_aligned = 1; use_ct = 1;
    } else if (ws_size >= CB + ZZ) {          // C in out+1, CT in ws
        Cm = out + 1; CT = (float*)ws; zz = (float*)(ws + CB);
        c_aligned = 0; use_ct = 1;
    } else {                                  // C in out+1, no CT (strided)
        Cm = out + 1; CT = nullptr; zz = (float*)ws;
        c_aligned = 0; use_ct = 0;
    }
    // layout (floats): slotsA[0,8192) slotsB[8192,16384)  (256 x 128B each)
    unsigned long long* slotsA = (unsigned long long*)zz;
    unsigned long long* slotsB = (unsigned long long*)(zz + 8192);

    hipLaunchKernelGGL(build_cost, dim3(32, 32), dim3(TPB_B), 0, stream,
                       x, y, Cm, CT, zz, c_aligned, use_ct);

    const float* Cmc = Cm;
    const float* CTc = CT;
    void* args[] = { (void*)&Cmc, (void*)&CTc, (void*)&slotsA, (void*)&slotsB,
                     (void*)&out, (void*)&c_aligned, (void*)&use_ct };
    hipLaunchCooperativeKernel((void*)sinkhorn_main, dim3(NB), dim3(TPB),
                               args, 0, stream);
}

// Round 7
// 1058.239 us; speedup vs baseline: 1.2793x; 1.2793x over previous
//
#include <hip/hip_runtime.h>
#include <cstddef>

static constexpr int   NN      = 2048;
static constexpr int   TPB_B   = 256;   // build_cost block
static constexpr int   TPB     = 512;   // main kernel block (8 waves)
static constexpr int   NWB     = TPB / 64;          // 8 waves/block
static constexpr int   NB      = 256;               // main grid blocks (1/CU)
static constexpr int   SLOTSTR = 16;                // u64 stride: 1 slot / 128B line
static constexpr int   MAX_IT  = 100;
static constexpr float EPS     = 0.1f;
static constexpr float INV_EPS = 10.0f;
// logf(1/2048 + 1e-8)
static constexpr float LOG_AB  = -7.6245985063594f;
static constexpr float THRESH  = 0.1f;

#define ALOAD(p)     __hip_atomic_load((p),  __ATOMIC_RELAXED, __HIP_MEMORY_SCOPE_AGENT)
#define ASTORE(p, x) __hip_atomic_store((p), (x), __ATOMIC_RELAXED, __HIP_MEMORY_SCOPE_AGENT)

// ---------------------------------------------------------------------------
// Cost matrix build + state zeroing. C[i][j] = sum_d (x[i,d]-y[j,d])^2.
// ---------------------------------------------------------------------------
__global__ __launch_bounds__(TPB_B)
void build_cost(const float* __restrict__ x, const float* __restrict__ y,
                float* __restrict__ C, float* __restrict__ CT,
                float* __restrict__ zz, int c_aligned, int use_ct)
{
    __shared__ float xs[64][65];
    __shared__ float ys[64][65];
    const int t  = threadIdx.x;
    const int bi = blockIdx.y, bj = blockIdx.x;

    // block (0,0) zeroes state region: u0|v|u1|flag|slots in [0,16384) floats
    if (bi == 0 && bj == 0)
        for (int idx = t; idx < 16384; idx += TPB_B) zz[idx] = 0.0f;

#pragma unroll
    for (int k = 0; k < 16; ++k) {
        int idx = t + TPB_B * k;
        int r = idx >> 6, c = idx & 63;
        xs[r][c] = x[(size_t)(bi * 64 + r) * 64 + c];
        ys[r][c] = y[(size_t)(bj * 64 + r) * 64 + c];
    }
    __syncthreads();

    const int ti0 = (t >> 4) * 4;
    const int tj0 = (t & 15) * 4;
    float acc[4][4] = {};
#pragma unroll 8
    for (int d = 0; d < 64; ++d) {
        float xv[4], yv[4];
#pragma unroll
        for (int k = 0; k < 4; ++k) xv[k] = xs[ti0 + k][d];
#pragma unroll
        for (int l = 0; l < 4; ++l) yv[l] = ys[tj0 + l][d];
#pragma unroll
        for (int k = 0; k < 4; ++k)
#pragma unroll
            for (int l = 0; l < 4; ++l) {
                float df = xv[k] - yv[l];
                acc[k][l] = fmaf(df, df, acc[k][l]);
            }
    }

#pragma unroll
    for (int k = 0; k < 4; ++k) {
        size_t off = (size_t)(bi * 64 + ti0 + k) * NN + bj * 64 + tj0;
        if (c_aligned) {
            *(float4*)(C + off) = make_float4(acc[k][0], acc[k][1], acc[k][2], acc[k][3]);
        } else {
            C[off + 0] = acc[k][0]; C[off + 1] = acc[k][1];
            C[off + 2] = acc[k][2]; C[off + 3] = acc[k][3];
        }
    }
    if (use_ct) {
#pragma unroll
        for (int l = 0; l < 4; ++l) {
            size_t off = (size_t)(bj * 64 + tj0 + l) * NN + bi * 64 + ti0;
            *(float4*)(CT + off) = make_float4(acc[0][l], acc[1][l], acc[2][l], acc[3][l]);
        }
    }
}

// ---------------------------------------------------------------------------
// Helpers
// ---------------------------------------------------------------------------
__device__ __forceinline__ void load_row32(const float* row, int lane,
                                           int aligned, float c[32])
{
    if (aligned) {
        const float4* r4 = (const float4*)row;
#pragma unroll
        for (int k = 0; k < 8; ++k) {
            float4 A = r4[lane + 64 * k];
            c[4*k+0] = A.x; c[4*k+1] = A.y; c[4*k+2] = A.z; c[4*k+3] = A.w;
        }
    } else {
#pragma unroll
        for (int k = 0; k < 8; ++k) {
            const float* p = row + 4 * (lane + 64 * k);
            c[4*k+0] = p[0]; c[4*k+1] = p[1]; c[4*k+2] = p[2]; c[4*k+3] = p[3];
        }
    }
}

// stage 2048 floats from global (coherent bypass u64 loads) into LDS
__device__ __forceinline__ void stage2048(const float* gp, float* sv, int t)
{
    const unsigned long long* g8 = (const unsigned long long*)gp;
    unsigned long long*       s8 = (unsigned long long*)sv;
#pragma unroll
    for (int k = 0; k < 2; ++k) {
        int idx = t + TPB * k;          // 0..1023
        s8[idx] = ALOAD(&g8[idx]);
    }
    __syncthreads();
}

__device__ __forceinline__ void lds_row32(const float* sv, int lane, float b[32])
{
    const float4* s4 = (const float4*)sv;
#pragma unroll
    for (int k = 0; k < 8; ++k) {
        float4 A = s4[lane + 64 * k];
        b[4*k+0] = A.x; b[4*k+1] = A.y; b[4*k+2] = A.z; b[4*k+3] = A.w;
    }
}

// wave-level lse of (b-c)*INV_EPS over 2048 elems (32/lane); result on all
// lanes. Two-phase: max-reduce (shfl only), then sum-reduce — avoids the
// 2-exp rescale per butterfly stage of the online-merge form.
__device__ __forceinline__ float wave_lse(float c[32], const float b[32])
{
#pragma unroll
    for (int k = 0; k < 32; ++k) c[k] = (b[k] - c[k]) * INV_EPS;
    float M = c[0];
#pragma unroll
    for (int k = 1; k < 32; ++k) M = fmaxf(M, c[k]);
#pragma unroll
    for (int off = 1; off < 64; off <<= 1) M = fmaxf(M, __shfl_xor(M, off));
    float s = 0.0f;
#pragma unroll
    for (int k = 0; k < 32; ++k) s += __expf(c[k] - M);
#pragma unroll
    for (int off = 1; off < 64; off <<= 1) s += __shfl_xor(s, off);
    return M + __logf(s);
}

// ---------------------------------------------------------------------------
// Two-hop fence-free barrier, poll-disciplined.
//  post:   every thread vmcnt(0)-drains its coherent stores; t0 posts this
//          block's slot {epoch|pdiff} on its own 128B line.
//  hop 1:  block0 wave0 polls all 256 slots (4/lane, pipelined), reduces
//          pdiffs, posts the single release flag {epoch|sum}.
//  hop 2:  ONLY WAVE 0 of each block polls the flag (one coalesced
//          same-address request per block per RTT — no LLC oversubscription;
//          R5 had all 512 threads polling, R6 had all-to-all: both queued at
//          the LLC). Result broadcast to the other 7 waves via LDS.
// Fence-free: RELAXED+AGENT bypass ops only -> per-XCD L2 (holding C/CT)
// is never invalidated.
// ---------------------------------------------------------------------------
__device__ __forceinline__ float gbar(unsigned long long* slots,
                                      unsigned long long* flagp,
                                      unsigned epoch, const float* swave,
                                      float* sred)
{
    const int t = threadIdx.x;
    asm volatile("s_waitcnt vmcnt(0)" ::: "memory");
    __syncthreads();
    if (t == 0) {
        float p = 0.0f;
#pragma unroll
        for (int w = 0; w < NWB; ++w) p += swave[w];
        unsigned long long val = ((unsigned long long)epoch << 32) |
                                 (unsigned long long)__float_as_uint(p);
        ASTORE(&slots[(size_t)blockIdx.x * SLOTSTR], val);
    }
    if (blockIdx.x == 0 && t < 64) {
        float d;
        for (;;) {
            bool ok = true;
            d = 0.0f;
#pragma unroll
            for (int k = 0; k < 4; ++k) {
                unsigned long long s = ALOAD(&slots[(size_t)(4 * t + k) * SLOTSTR]);
                ok &= ((unsigned)(s >> 32) >= epoch);
                d += __uint_as_float((unsigned)s);
            }
            if (__ballot(ok) == ~0ull) break;
        }
#pragma unroll
        for (int off = 1; off < 64; off <<= 1) d += __shfl_xor(d, off);
        if (t == 0) {
            unsigned long long val = ((unsigned long long)epoch << 32) |
                                     (unsigned long long)__float_as_uint(d);
            ASTORE(flagp, val);
        }
    }
    if (t < 64) {                       // wave 0 only: 1 request/block/RTT
        unsigned long long f;
        for (;;) {
            f = ALOAD(flagp);
            if ((unsigned)(f >> 32) >= epoch) break;
        }
        if (t == 0) *sred = __uint_as_float((unsigned)f);
    }
    __syncthreads();
    return *sred;
}

// ---------------------------------------------------------------------------
// Main cooperative kernel. 256 blocks x 512 thr; wave w of block b owns row
// i = b*8 + w (its 16 KB of C rows stay L1/L2-resident: no fences).
// Cm may alias out+1.
// ---------------------------------------------------------------------------
__global__ __launch_bounds__(TPB)
void sinkhorn_main(const float* Cm, const float* __restrict__ CT,
                   float* __restrict__ u0, float* __restrict__ u1,
                   float* __restrict__ v,
                   unsigned long long* __restrict__ slots,
                   unsigned long long* __restrict__ flagp,
                   float* out, int c_aligned, int use_ct)
{
    __shared__ float sv[2048];
    __shared__ float swave[NWB];
    __shared__ float sred;
    const int t    = threadIdx.x;
    const int lane = t & 63;
    const int w    = t >> 6;
    const int b    = blockIdx.x;
    const int i    = b * NWB + w;       // this wave's row == col index

    unsigned ep = 0;

    float* ucur  = u0;
    float* unext = u1;
    float* ulast = u1;

    for (int it = 0; it < MAX_IT; ++it) {
        // ---- row pass: u_new[i] = eps*(log_a - lse_j((v_j - C_ij)/eps))
        float rowdiff;
        {
            float uold = 0.0f;
            if (lane == 0) uold = ALOAD(&ucur[i]);   // prefetch, hidden by stage
            stage2048(v, sv, t);
            float b32[32], c32[32];
            lds_row32(sv, lane, b32);
            load_row32(Cm + (size_t)i * NN, lane, c_aligned, c32);
            float lse = wave_lse(c32, b32);
            if (lane == 0) {
                float un = EPS * (LOG_AB - lse);
                ASTORE(&unext[i], un);
                swave[w] = fabsf(un - uold);
            }
            rowdiff = gbar(slots, flagp, ++ep, swave, &sred);
        }

        // ---- col pass: v_new[j] = eps*(log_b - lse_i((u_i - C_ij)/eps))
        float coldiff;
        {
            float vold = 0.0f;
            if (lane == 0) vold = ALOAD(&v[i]);
            stage2048(unext, sv, t);
            float b32[32], c32[32];
            lds_row32(sv, lane, b32);
            if (use_ct) {
                load_row32(CT + (size_t)i * NN, lane, 1, c32);
            } else {
#pragma unroll
                for (int k = 0; k < 8; ++k)
#pragma unroll
                    for (int kk = 0; kk < 4; ++kk)
                        c32[4*k+kk] = Cm[(size_t)(4 * (lane + 64 * k) + kk) * NN + i];
            }
            float lse = wave_lse(c32, b32);
            if (lane == 0) {
                float vn = EPS * (LOG_AB - lse);
                ASTORE(&v[i], vn);
                swave[w] = fabsf(vn - vold);
            }
            coldiff = gbar(slots, flagp, ++ep, swave, &sred);
        }

        ulast = unext;
        if (rowdiff + coldiff < THRESH) break;   // uniform across grid
        float* tmp = ucur; ucur = unext; unext = tmp;
    }

    // ---- epilogue: pi = exp((u_i + v_j - C_ij)/eps), cost = sum(pi*C)
    float cpart = 0.0f;
    {
        float ui_s = 0.0f;
        if (lane == 0) ui_s = ALOAD(&ulast[i]);
        stage2048(v, sv, t);
        float ui = __shfl(ui_s, 0);
        float b32[32], c32[32];
        lds_row32(sv, lane, b32);
        load_row32(Cm + (size_t)i * NN, lane, c_aligned, c32);
        float* orow = out + 1 + (size_t)i * NN;
#pragma unroll
        for (int k = 0; k < 8; ++k) {
#pragma unroll
            for (int kk = 0; kk < 4; ++kk) {
                float cc = c32[4*k+kk];
                float p  = __expf((ui + b32[4*k+kk] - cc) * INV_EPS);
                cpart = fmaf(p, cc, cpart);
                orow[4 * (lane + 64 * k) + kk] = p;  // safe even if Cm==out+1
            }
        }
    }
#pragma unroll
    for (int off = 1; off < 64; off <<= 1) cpart += __shfl_xor(cpart, off);
    if (lane == 0) swave[w] = cpart;
    float total = gbar(slots, flagp, ++ep, swave, &sred);
    if (b == 0 && t == 0) out[0] = total;
}

// ---------------------------------------------------------------------------
extern "C" void kernel_launch(void* const* d_in, const int* in_sizes, int n_in,
                              void* d_out, int out_size, void* d_ws, size_t ws_size,
                              hipStream_t stream)
{
    (void)in_sizes; (void)n_in; (void)out_size;
    const float* x = (const float*)d_in[0];
    const float* y = (const float*)d_in[1];
    float* out = (float*)d_out;
    char*  ws  = (char*)d_ws;

    const size_t CB = (size_t)NN * NN * sizeof(float);   // 16 MiB
    const size_t ZZ = 128 * 1024;

    float *Cm, *CT, *zz;
    int c_aligned, use_ct;
    if (ws_size >= 2 * CB + ZZ) {             // preferred: C, CT, state in ws
        Cm = (float*)ws; CT = (float*)(ws + CB); zz = (float*)(ws + 2 * CB);
        c_aligned = 1; use_ct = 1;
    } else if (ws_size >= CB + ZZ) {          // C in out+1, CT in ws
        Cm = out + 1; CT = (float*)ws; zz = (float*)(ws + CB);
        c_aligned = 0; use_ct = 1;
    } else {                                  // C in out+1, no CT (strided)
        Cm = out + 1; CT = nullptr; zz = (float*)ws;
        c_aligned = 0; use_ct = 0;
    }
    // layout (floats): u0[0,2048) v[2048,4096) u1[4096,6144)
    //                  flag @6272 (own line)   slots[8192,16384) (256x128B)
    float*              u0    = zz;
    float*              v     = zz + 2048;
    float*              u1    = zz + 4096;
    unsigned long long* flagp = (unsigned long long*)(zz + 6272);
    unsigned long long* slots = (unsigned long long*)(zz + 8192);

    hipLaunchKernelGGL(build_cost, dim3(32, 32), dim3(TPB_B), 0, stream,
                       x, y, Cm, CT, zz, c_aligned, use_ct);

    const float* Cmc = Cm;
    const float* CTc = CT;
    void* args[] = { (void*)&Cmc, (void*)&CTc, (void*)&u0, (void*)&u1,
                     (void*)&v, (void*)&slots, (void*)&flagp,
                     (void*)&out, (void*)&c_aligned, (void*)&use_ct };
    hipLaunchCooperativeKernel((void*)sinkhorn_main, dim3(NB), dim3(TPB),
                               args, 0, stream);
}

// Round 8
// 827.123 us; speedup vs baseline: 1.6368x; 1.2794x over previous
//
#include <hip/hip_runtime.h>
#include <cstddef>

static constexpr int   NN      = 2048;
static constexpr int   TPB_B   = 256;   // build_cost block
static constexpr int   TPB     = 512;   // main kernel block (8 waves)
static constexpr int   NWB     = TPB / 64;          // 8 waves/block
static constexpr int   NB      = 256;               // main grid blocks (1/CU)
static constexpr int   MAX_IT  = 100;
static constexpr float EPS     = 0.1f;
static constexpr float INV_EPS = 10.0f;
// logf(1/2048 + 1e-8)
static constexpr float LOG_AB  = -7.6245985063594f;
static constexpr float THRESH  = 0.1f;

#define ALOAD(p)     __hip_atomic_load((p),  __ATOMIC_RELAXED, __HIP_MEMORY_SCOPE_AGENT)
#define ASTORE(p, x) __hip_atomic_store((p), (x), __ATOMIC_RELAXED, __HIP_MEMORY_SCOPE_AGENT)

// ---------------------------------------------------------------------------
// Cost matrix build + state zeroing. C[i][j] = sum_d (x[i,d]-y[j,d])^2.
// ---------------------------------------------------------------------------
__global__ __launch_bounds__(TPB_B)
void build_cost(const float* __restrict__ x, const float* __restrict__ y,
                float* __restrict__ C, float* __restrict__ CT,
                float* __restrict__ zz, int c_aligned, int use_ct)
{
    __shared__ float xs[64][65];
    __shared__ float ys[64][65];
    const int t  = threadIdx.x;
    const int bi = blockIdx.y, bj = blockIdx.x;

    // block (0,0) zeroes signal region: valA|valB|rotR|rotC|cost = 6400 u64
    if (bi == 0 && bj == 0)
        for (int idx = t; idx < 16384; idx += TPB_B) zz[idx] = 0.0f;

#pragma unroll
    for (int k = 0; k < 16; ++k) {
        int idx = t + TPB_B * k;
        int r = idx >> 6, c = idx & 63;
        xs[r][c] = x[(size_t)(bi * 64 + r) * 64 + c];
        ys[r][c] = y[(size_t)(bj * 64 + r) * 64 + c];
    }
    __syncthreads();

    const int ti0 = (t >> 4) * 4;
    const int tj0 = (t & 15) * 4;
    float acc[4][4] = {};
#pragma unroll 8
    for (int d = 0; d < 64; ++d) {
        float xv[4], yv[4];
#pragma unroll
        for (int k = 0; k < 4; ++k) xv[k] = xs[ti0 + k][d];
#pragma unroll
        for (int l = 0; l < 4; ++l) yv[l] = ys[tj0 + l][d];
#pragma unroll
        for (int k = 0; k < 4; ++k)
#pragma unroll
            for (int l = 0; l < 4; ++l) {
                float df = xv[k] - yv[l];
                acc[k][l] = fmaf(df, df, acc[k][l]);
            }
    }

#pragma unroll
    for (int k = 0; k < 4; ++k) {
        size_t off = (size_t)(bi * 64 + ti0 + k) * NN + bj * 64 + tj0;
        if (c_aligned) {
            *(float4*)(C + off) = make_float4(acc[k][0], acc[k][1], acc[k][2], acc[k][3]);
        } else {
            C[off + 0] = acc[k][0]; C[off + 1] = acc[k][1];
            C[off + 2] = acc[k][2]; C[off + 3] = acc[k][3];
        }
    }
    if (use_ct) {
#pragma unroll
        for (int l = 0; l < 4; ++l) {
            size_t off = (size_t)(bj * 64 + tj0 + l) * NN + bi * 64 + ti0;
            *(float4*)(CT + off) = make_float4(acc[0][l], acc[1][l], acc[2][l], acc[3][l]);
        }
    }
}

// ---------------------------------------------------------------------------
// Helpers
// ---------------------------------------------------------------------------
__device__ __forceinline__ void load_row32(const float* row, int lane,
                                           int aligned, float c[32])
{
    if (aligned) {
        const float4* r4 = (const float4*)row;
#pragma unroll
        for (int k = 0; k < 8; ++k) {
            float4 A = r4[lane + 64 * k];
            c[4*k+0] = A.x; c[4*k+1] = A.y; c[4*k+2] = A.z; c[4*k+3] = A.w;
        }
    } else {
#pragma unroll
        for (int k = 0; k < 8; ++k) {
            const float* p = row + 4 * (lane + 64 * k);
            c[4*k+0] = p[0]; c[4*k+1] = p[1]; c[4*k+2] = p[2]; c[4*k+3] = p[3];
        }
    }
}

__device__ __forceinline__ void lds_row32(const float* sv, int lane, float b[32])
{
    const float4* s4 = (const float4*)sv;
#pragma unroll
    for (int k = 0; k < 8; ++k) {
        float4 A = s4[lane + 64 * k];
        b[4*k+0] = A.x; b[4*k+1] = A.y; b[4*k+2] = A.z; b[4*k+3] = A.w;
    }
}

// wave-level lse of (b-c)*INV_EPS over 2048 elems; result on ALL lanes.
// Max deferred-scale trick: max over (b-c) first (INV_EPS>0, monotone).
__device__ __forceinline__ float wave_lse(const float c[32], const float b[32])
{
    float M = b[0] - c[0];
#pragma unroll
    for (int k = 1; k < 32; ++k) M = fmaxf(M, b[k] - c[k]);
#pragma unroll
    for (int off = 1; off < 64; off <<= 1) M = fmaxf(M, __shfl_xor(M, off));
    float Ms = M * INV_EPS;
    float s = 0.0f;
#pragma unroll
    for (int k = 0; k < 32; ++k) s += __expf(fmaf(b[k] - c[k], INV_EPS, -Ms));
#pragma unroll
    for (int off = 1; off < 64; off <<= 1) s += __shfl_xor(s, off);
    return Ms + __logf(s);
}

// ---------------------------------------------------------------------------
// Main cooperative kernel. 256 blocks x 512 thr; wave w of block b owns
// row/col i = b*8+w. C row + CT col live in REGISTERS (loop-invariant).
// All cross-block state is self-validating u64 {epoch|f32} bypass atomics:
//  - valA/valB: 2048 packed u64 (u resp. v values). Post = ONE 8B store
//    (epoch+value indivisible -> no drain, no flag, no separate data fetch).
//    Readers: thread t polls its own 4 u64s (data-dependent exit) -> sv LDS.
//    Reuse safe: block posts val(e+1) only after polling ALL of the other
//    array's epoch-e values, which requires every block read this array(e).
//  - rotR/rotC[4][256]: per-block pdiffs, 4-deep rotation (3-iter reuse
//    distance). Convergence check DEFERRED one half-iter (after next row
//    compute, before post) -> latency hidden; break state = pre-update
//    u_keep/v_keep/sv, exactly the reference's freeze semantics.
// Cm may alias out+1 (crow is register-resident before any overwrite).
// ---------------------------------------------------------------------------
__global__ __launch_bounds__(TPB)
void sinkhorn_main(const float* Cm, const float* __restrict__ CT,
                   unsigned long long* __restrict__ valA,
                   unsigned long long* __restrict__ valB,
                   unsigned long long* __restrict__ rotR,
                   unsigned long long* __restrict__ rotC,
                   unsigned long long* __restrict__ costb,
                   float* out, int c_aligned, int use_ct)
{
    __shared__ float sv[2048];
    __shared__ float swave[NWB];
    __shared__ float sdw[NWB];
    __shared__ float sred4[4];
    __shared__ float sdiff;
    const int t = threadIdx.x, lane = t & 63, w = t >> 6, b = blockIdx.x;
    const int i = b * NWB + w;

    // loop-invariant C row / CT col -> registers
    float crow[32], ccol[32];
    load_row32(Cm + (size_t)i * NN, lane, c_aligned, crow);
    if (use_ct) {
        load_row32(CT + (size_t)i * NN, lane, 1, ccol);
    } else {
#pragma unroll
        for (int k = 0; k < 8; ++k)
#pragma unroll
            for (int kk = 0; kk < 4; ++kk)
                ccol[4*k+kk] = Cm[(size_t)(4 * (lane + 64 * k) + kk) * NN + i];
    }

    for (int k = t; k < 2048; k += TPB) sv[k] = 0.0f;   // v(0) = 0
    __syncthreads();

    float u_keep = 0.0f, v_keep = 0.0f;
    float b32[32];

    for (int it = 0; it < MAX_IT; ++it) {
        const unsigned ep = (unsigned)(it + 1);

        // ---- row compute: u(ep)_i from sv = v(it)
        lds_row32(sv, lane, b32);
        float lse   = wave_lse(crow, b32);
        float u_new = EPS * (LOG_AB - lse);          // uniform on all lanes
        float pdr   = fabsf(u_new - u_keep);

        // ---- deferred convergence check of iteration `it` (epoch it)
        if (it >= 1) {
            if (t < 256) {
                unsigned long long r1, r2;
                const int ri = (it & 3) * 256 + t;
                for (;;) { r1 = ALOAD(&rotR[ri]);
                           if ((unsigned)(r1 >> 32) >= (unsigned)it) break; }
                for (;;) { r2 = ALOAD(&rotC[ri]);
                           if ((unsigned)(r2 >> 32) >= (unsigned)it) break; }
                float d = __uint_as_float((unsigned)r1) +
                          __uint_as_float((unsigned)r2);
#pragma unroll
                for (int off = 1; off < 64; off <<= 1) d += __shfl_xor(d, off);
                if (lane == 0) sred4[w] = d;
            }
            __syncthreads();
            if (t == 0) sdiff = sred4[0] + sred4[1] + sred4[2] + sred4[3];
            __syncthreads();
            if (sdiff < THRESH) break;   // state: u_keep=u(it), v_keep, sv=v(it)
        }
        u_keep = u_new;

        // ---- post A(ep): self-validating values + block pdiff
        if (lane == 0) { swave[w] = u_new; sdw[w] = pdr; }
        __syncthreads();
        if (t < NWB)
            ASTORE(&valA[b * NWB + t],
                   ((unsigned long long)ep << 32) | __float_as_uint(swave[t]));
        if (t == 0) {
            float ps = 0.0f;
#pragma unroll
            for (int k = 0; k < NWB; ++k) ps += sdw[k];
            ASTORE(&rotR[(ep & 3) * 256 + b],
                   ((unsigned long long)ep << 32) | __float_as_uint(ps));
        }
        // ---- poll A -> sv = u(ep)  (one LLC RTT; detection IS the fetch)
        {
            unsigned long long d0, d1, d2, d3;
            const int base = 4 * t;
            for (;;) {
                d0 = ALOAD(&valA[base + 0]); d1 = ALOAD(&valA[base + 1]);
                d2 = ALOAD(&valA[base + 2]); d3 = ALOAD(&valA[base + 3]);
                bool ok = ((unsigned)(d0 >> 32) >= ep) & ((unsigned)(d1 >> 32) >= ep)
                        & ((unsigned)(d2 >> 32) >= ep) & ((unsigned)(d3 >> 32) >= ep);
                if (ok) break;
            }
            ((float4*)sv)[t] = make_float4(__uint_as_float((unsigned)d0),
                                           __uint_as_float((unsigned)d1),
                                           __uint_as_float((unsigned)d2),
                                           __uint_as_float((unsigned)d3));
        }
        __syncthreads();

        // ---- col compute: v(ep)_j from sv = u(ep)
        lds_row32(sv, lane, b32);
        lse = wave_lse(ccol, b32);
        float v_new = EPS * (LOG_AB - lse);
        float pdc   = fabsf(v_new - v_keep);
        v_keep = v_new;

        if (lane == 0) { swave[w] = v_new; sdw[w] = pdc; }
        __syncthreads();
        if (t < NWB)
            ASTORE(&valB[b * NWB + t],
                   ((unsigned long long)ep << 32) | __float_as_uint(swave[t]));
        if (t == 0) {
            float ps = 0.0f;
#pragma unroll
            for (int k = 0; k < NWB; ++k) ps += sdw[k];
            ASTORE(&rotC[(ep & 3) * 256 + b],
                   ((unsigned long long)ep << 32) | __float_as_uint(ps));
        }
        // ---- poll B -> sv = v(ep)
        {
            unsigned long long d0, d1, d2, d3;
            const int base = 4 * t;
            for (;;) {
                d0 = ALOAD(&valB[base + 0]); d1 = ALOAD(&valB[base + 1]);
                d2 = ALOAD(&valB[base + 2]); d3 = ALOAD(&valB[base + 3]);
                bool ok = ((unsigned)(d0 >> 32) >= ep) & ((unsigned)(d1 >> 32) >= ep)
                        & ((unsigned)(d2 >> 32) >= ep) & ((unsigned)(d3 >> 32) >= ep);
                if (ok) break;
            }
            ((float4*)sv)[t] = make_float4(__uint_as_float((unsigned)d0),
                                           __uint_as_float((unsigned)d1),
                                           __uint_as_float((unsigned)d2),
                                           __uint_as_float((unsigned)d3));
        }
        __syncthreads();
    }

    // ---- epilogue: pi = exp((u_i + v_j - C_ij)/eps), cost = sum(pi*C)
    float cpart = 0.0f;
    {
        lds_row32(sv, lane, b32);          // sv = final v
        const float ui = u_keep;           // final u_i (wave-uniform)
        float* orow = out + 1 + (size_t)i * NN;
#pragma unroll
        for (int k = 0; k < 8; ++k) {
#pragma unroll
            for (int kk = 0; kk < 4; ++kk) {
                float cc = crow[4*k+kk];
                float p  = __expf((ui + b32[4*k+kk] - cc) * INV_EPS);
                cpart = fmaf(p, cc, cpart);
                orow[4 * (lane + 64 * k) + kk] = p;  // crow in regs: alias-safe
            }
        }
    }
#pragma unroll
    for (int off = 1; off < 64; off <<= 1) cpart += __shfl_xor(cpart, off);
    if (lane == 0) sdw[w] = cpart;
    __syncthreads();
    if (t == 0) {
        float pc = 0.0f;
#pragma unroll
        for (int k = 0; k < NWB; ++k) pc += sdw[k];
        ASTORE(&costb[b], (1ull << 32) | __float_as_uint(pc));
    }
    if (b == 0) {                          // block 0 gathers the cost total
        if (t < 256) {
            unsigned long long h;
            for (;;) { h = ALOAD(&costb[t]); if ((unsigned)(h >> 32) >= 1u) break; }
            float pc = __uint_as_float((unsigned)h);
#pragma unroll
            for (int off = 1; off < 64; off <<= 1) pc += __shfl_xor(pc, off);
            if (lane == 0) sred4[w] = pc;
        }
        __syncthreads();
        if (t == 0) out[0] = sred4[0] + sred4[1] + sred4[2] + sred4[3];
    }
}

// ---------------------------------------------------------------------------
extern "C" void kernel_launch(void* const* d_in, const int* in_sizes, int n_in,
                              void* d_out, int out_size, void* d_ws, size_t ws_size,
                              hipStream_t stream)
{
    (void)in_sizes; (void)n_in; (void)out_size;
    const float* x = (const float*)d_in[0];
    const float* y = (const float*)d_in[1];
    float* out = (float*)d_out;
    char*  ws  = (char*)d_ws;

    const size_t CB = (size_t)NN * NN * sizeof(float);   // 16 MiB
    const size_t ZZ = 128 * 1024;

    float *Cm, *CT, *zz;
    int c_aligned, use_ct;
    if (ws_size >= 2 * CB + ZZ) {             // preferred: C, CT, state in ws
        Cm = (float*)ws; CT = (float*)(ws + CB); zz = (float*)(ws + 2 * CB);
        c_aligned = 1; use_ct = 1;
    } else if (ws_size >= CB + ZZ) {          // C in out+1, CT in ws
        Cm = out + 1; CT = (float*)ws; zz = (float*)(ws + CB);
        c_aligned = 0; use_ct = 1;
    } else {                                  // C in out+1, no CT (strided)
        Cm = out + 1; CT = nullptr; zz = (float*)ws;
        c_aligned = 0; use_ct = 0;
    }
    // u64 layout in zz: valA[0,2048) valB[2048,4096) rotR[4096,5120)
    //                   rotC[5120,6144) costb[6144,6400)
    unsigned long long* zz64  = (unsigned long long*)zz;
    unsigned long long* valA  = zz64;
    unsigned long long* valB  = zz64 + 2048;
    unsigned long long* rotR  = zz64 + 4096;
    unsigned long long* rotC  = zz64 + 5120;
    unsigned long long* costb = zz64 + 6144;

    hipLaunchKernelGGL(build_cost, dim3(32, 32), dim3(TPB_B), 0, stream,
                       x, y, Cm, CT, zz, c_aligned, use_ct);

    const float* Cmc = Cm;
    const float* CTc = CT;
    void* args[] = { (void*)&Cmc, (void*)&CTc, (void*)&valA, (void*)&valB,
                     (void*)&rotR, (void*)&rotC, (void*)&costb,
                     (void*)&out, (void*)&c_aligned, (void*)&use_ct };
    hipLaunchCooperativeKernel((void*)sinkhorn_main, dim3(NB), dim3(TPB),
                               args, 0, stream);
}